// Round 2
// baseline (389.113 us; speedup 1.0000x reference)
//
#include <hip/hip_runtime.h>

// Stencil gather: out[b,j,k,{center,up,right,down,left}], edge-replicated.
// B=16, H=1024, W=1024, f32. 64 MiB read + 320 MiB write -> ~61 us floor.
// Graph dur = ~209 us harness poison-fill (fixed) + stencil time.
//
// Round 2 post-mortem: persistent 4-wave blocks with per-row barriers made
// it WORSE (378.7 vs 367.6) despite less read traffic -> the limiter is not
// bandwidth or feed-continuity; it's the block-wide barrier convoy (each
// __syncthreads forces s_waitcnt vmcnt(0): 4 waves wait on slowest load AND
// full nt-store retirement, every row). The harness fill does 6.4 TB/s at
// 10% occupancy with independent waves + long runs of PLAIN stores.
//
// Round 3 (this version): wave-autonomous streaming. 1 block = 1 wave =
// one 8-row band. ZERO __syncthreads:
//  - lane l owns pixels 16l..16l+15 of the row; rolling regs u/c/d
//    (4 x float4 each) + 1-row prefetch -> each input row loaded once.
//  - strip-edge neighbors via __shfl_up/down of center regs (no loads).
//  - pixel-major -> coalesced transpose through WAVE-PRIVATE LDS (ordered
//    by same-wave lgkmcnt only). Lane stride = 21 f4 (336B): 21 mod 8 = 5,
//    coprime -> conflict-free b128 writes; reads are near-contiguous.
//    21504 B/wave -> 7 independent waves/CU.
//  - per row: 20 back-to-back coalesced PLAIN float4 stores (1 KiB/instr).
//    nt dropped to match the fill's demonstrated-fast store path.

typedef float f4v __attribute__((ext_vector_type(4)));

constexpr int ROWS = 8;
constexpr int LSTRIDE_F4 = 21;   // 20 used + 1 pad f4 per lane region

__global__ __launch_bounds__(64) void stencil5_kernel(
    const float* __restrict__ in, float* __restrict__ out) {
    constexpr int H = 1024;

    __shared__ f4v lds[64 * LSTRIDE_F4];   // 21504 B

    const int l  = threadIdx.x;            // lane 0..63
    const int g0 = blockIdx.x * ROWS;      // first global row of band
    const int j0 = g0 & (H - 1);           // row within image (bands never cross images)
    const long imgrow0 = (long)(g0 - j0);  // first row of this image

    const float* pk = in + (imgrow0 << 10) + (l << 4);   // col 16*l strip

    // Rolling rows: u = j0-1 (clamped -> edge-replication), c = j0, d = j0+1.
    f4v u[4], c[4], d[4];
    {
        const float* pu = pk + ((long)(j0 > 0 ? j0 - 1 : 0) << 10);
        const float* pc = pk + ((long)j0 << 10);
        const float* pd = pk + ((long)(j0 + 1) << 10);   // j0+1 <= H-1 always
        #pragma unroll
        for (int q = 0; q < 4; ++q) u[q] = *(const f4v*)(pu + 4 * q);
        #pragma unroll
        for (int q = 0; q < 4; ++q) c[q] = *(const f4v*)(pc + 4 * q);
        #pragma unroll
        for (int q = 0; q < 4; ++q) d[q] = *(const f4v*)(pd + 4 * q);
    }

    f4v* myl = lds + LSTRIDE_F4 * l;

    #pragma unroll
    for (int r = 0; r < ROWS; ++r) {
        const int j = j0 + r;

        // Prefetch row j+2 = next iteration's down-row; clamp to H-1 gives
        // exact edge-replication (down of last row = itself = center).
        const int jn = (j + 2 < H) ? (j + 2) : (H - 1);
        const float* pn = pk + ((long)jn << 10);
        f4v n[4];
        #pragma unroll
        for (int q = 0; q < 4; ++q) n[q] = *(const f4v*)(pn + 4 * q);

        // Strip-edge neighbors from center regs via cross-lane shuffle.
        float lx = __shfl_up(c[3][3], 1);     // lane l-1's col 16l-1
        lx = (l == 0) ? c[0][0] : lx;         // image col 0 -> center
        float rx = __shfl_down(c[0][0], 1);   // lane l+1's col 16l+16
        rx = (l == 63) ? c[3][3] : rx;        // image col 1023 -> center

        // Build this lane's 80 output floats (16 px * 5 ch, pixel-major
        // channel-minor) as 20 f4 LDS writes. All indices compile-time.
        #pragma unroll
        for (int s = 0; s < 20; ++s) {
            f4v v;
            #pragma unroll
            for (int e = 0; e < 4; ++e) {
                const int f = 4 * s + e;
                const int t = f / 5, ch = f % 5;
                float x;
                if (ch == 0)      x = c[t >> 2][t & 3];
                else if (ch == 1) x = u[t >> 2][t & 3];
                else if (ch == 2) x = (t < 15) ? c[(t + 1) >> 2][(t + 1) & 3] : rx;
                else if (ch == 3) x = d[t >> 2][t & 3];
                else              x = (t > 0) ? c[(t - 1) >> 2][(t - 1) & 3] : lx;
                v[e] = x;
            }
            myl[s] = v;   // ds_write_b128, imm offset; banks spread (stride 21)
        }
        // (compiler inserts lgkmcnt wait; same-wave -> no barrier needed)

        // Coalesced streaming store of the row's 20 KiB: f4 index m = l+64s,
        // located in padded LDS at lane m/20, slot m%20.
        f4v* orow = (f4v*)(out + (((long)(g0 + r)) << 10) * 5);
        #pragma unroll
        for (int s = 0; s < 20; ++s) {
            const int m  = l + 64 * s;
            const int w  = (m * 3277) >> 16;    // m/20, exact for m < 1310
            const int s0 = m - 20 * w;          // m%20
            orow[m] = lds[LSTRIDE_F4 * w + s0];
        }

        // Roll the row window (full unroll -> register renaming, no movs).
        #pragma unroll
        for (int q = 0; q < 4; ++q) { u[q] = c[q]; c[q] = d[q]; d[q] = n[q]; }
    }
}

extern "C" void kernel_launch(void* const* d_in, const int* in_sizes, int n_in,
                              void* d_out, int out_size, void* d_ws, size_t ws_size,
                              hipStream_t stream) {
    const float* in = (const float*)d_in[0];
    float* out = (float*)d_out;

    const int n = in_sizes[0];            // B*H*W = 16*1024*1024
    const int rows = n >> 10;             // 16384 image rows
    const int blocks = rows / ROWS;       // 2048 one-wave blocks

    stencil5_kernel<<<blocks, 64, 0, stream>>>(in, out);
}

// Round 5
// 374.738 us; speedup vs baseline: 1.0384x; 1.0384x over previous
//
#include <hip/hip_runtime.h>

// Stencil gather: out[b,j,k,{center,up,right,down,left}], edge-replicated.
// B=16, H=1024, W=1024, f32. 64 MiB read + 320 MiB write -> ~61 us floor at
// the 6.4 TB/s the harness's own poison-fill sustains on this same buffer.
//
// History: R0 (this structure, nt stores) 367.6 us graph = ~210 fill + ~157
// stencil. R1 persistent 4-wave bands: 378.7 (worse). R2 wave-autonomous,
// plain stores, but only 2 waves/SIMD: 389.1 (worse, latency-bound).
// Upstream restructures that cut read traffic and lengthened store runs
// both LOST -> the limiter is downstream. Single remaining un-isolated
// variable vs the 6.4 TB/s fill kernel: nontemporal stores.
// R3, R4: this exact kernel — bench infra failed twice both rounds (container
// acquire/push flake; kernel never executed). Resubmitting unchanged.
//
// R5 (this version): byte-identical to R0 except the 5 output stores are
// PLAIN (allocate in L2/LLC, write-combine) instead of nontemporal.
// Strict A/B on one variable.
//
// Mapping: 1 block (256 threads) = 1 image row = 1024 pixels = 20 KiB output.
//  Phase 1: thread i computes pixels [4i,4i+4) -> 5 float4s -> LDS at 80B*i.
//  Phase 2: barrier; thread i stores LDS float4 [i+256r] -> out float4
//           [block_base + i + 256r], r=0..4. Fully coalesced.

typedef float f4 __attribute__((ext_vector_type(4)));

__global__ __launch_bounds__(256) void stencil5_kernel(
    const float* __restrict__ in, float* __restrict__ out) {
    constexpr int W = 1024;
    constexpr int H = 1024;

    __shared__ float lds[256 * 20];   // 20 KiB -> 8 blocks/CU

    const int i   = threadIdx.x;
    const int row = blockIdx.x;        // global row in [0, B*H)
    const int k0  = i << 2;            // starting column (multiple of 4)
    const int j   = row & (H - 1);     // row within image

    const long base = ((long)row << 10);
    const float* prow = in + base + k0;

    // Center (16B-aligned).
    const float4 c = *(const float4*)prow;

    // Up / down rows, replicating the center row at borders (wave-uniform).
    const float* uptr = prow - ((j > 0)     ? W : 0);
    const float* dptr = prow + ((j < H - 1) ? W : 0);
    const float4 u = *(const float4*)uptr;
    const float4 d = *(const float4*)dptr;

    // Left neighbor of pixel0 / right neighbor of pixel3 (clamped address,
    // then per-lane select to center at the image border).
    float lx = prow[-(k0 > 0 ? 1 : 0)];
    lx = (k0 > 0) ? lx : c.x;
    float rw = prow[(k0 + 4 < W) ? 4 : 3];
    rw = (k0 + 4 < W) ? rw : c.w;

    // Per-pixel output (pixel-major, channel-minor), 20 floats:
    // [c.x,u.x,c.y,d.x,lx | c.y,u.y,c.z,d.y,c.x | c.z,u.z,c.w,d.z,c.y |
    //  c.w,u.w,rw,d.w,c.z]
    float4* l = (float4*)(lds + i * 20);
    l[0] = make_float4(c.x, u.x, c.y, d.x);
    l[1] = make_float4(lx,  c.y, u.y, c.z);
    l[2] = make_float4(d.y, c.x, c.z, u.z);
    l[3] = make_float4(c.w, d.z, c.y, c.w);
    l[4] = make_float4(u.w, rw,  d.w, c.z);

    __syncthreads();

    // Coalesced streaming store of the block's 20 KiB (1280 float4s).
    // PLAIN stores (the only change vs R0): let L2/LLC write-combine and
    // drain, matching the 6.4 TB/s fill-kernel store path.
    const f4* ls = (const f4*)lds;
    f4* o = (f4*)(out + base * 5);
    #pragma unroll
    for (int r = 0; r < 5; ++r) {
        o[i + 256 * r] = ls[i + 256 * r];
    }
}

extern "C" void kernel_launch(void* const* d_in, const int* in_sizes, int n_in,
                              void* d_out, int out_size, void* d_ws, size_t ws_size,
                              hipStream_t stream) {
    const float* in = (const float*)d_in[0];
    float* out = (float*)d_out;

    const int n = in_sizes[0];       // B*H*W = 16 * 1024 * 1024
    const int blocks = n >> 10;      // one block per 1024-pixel row = 16384

    stencil5_kernel<<<blocks, 256, 0, stream>>>(in, out);
}